// Round 20
// baseline (156.582 us; speedup 1.0000x reference)
//
#include <hip/hip_runtime.h>

#define HH 128
#define NN 64
#define LL 256
#define WCP 40    // Wc pitch in u16 (32 + 8 pad)

typedef __attribute__((ext_vector_type(8))) short bf8;
typedef __attribute__((ext_vector_type(4))) float f32x4;

__device__ inline ushort f2bf(float f) {
    uint x = __float_as_uint(f);
    return (ushort)((x + 0x7fffu + ((x >> 16) & 1u)) >> 16);
}
__device__ inline uint cvt_pk_bf16(float lo, float hi) {
    uint r;
    asm volatile("v_cvt_pk_bf16_f32 %0, %1, %2" : "=v"(r) : "v"(lo), "v"(hi));
    return r;
}
#define MFMA(a,b,c) __builtin_amdgcn_mfma_f32_16x16x32_bf16((a),(b),(c),0,0,0)

// Tap generation (proven R13 version). Parity-split pair tables per (s,h):
// arrg[(s*HH+h)*512 + j]       = rev[2j]   | rev[2j+1]<<16   (arrE)
// arrg[(s*HH+h)*512 + 256 + j] = rev[2j+1] | rev[2j+2]<<16   (arrO)
__global__ __launch_bounds__(512) void ssm_gen_fast(
    const float* __restrict__ A_re0, const float* __restrict__ A_im0,
    const float* __restrict__ C_re0, const float* __restrict__ C_im0,
    const float* __restrict__ log_dt0,
    const float* __restrict__ A_re1, const float* __restrict__ A_im1,
    const float* __restrict__ C_re1, const float* __restrict__ C_im1,
    const float* __restrict__ log_dt1,
    uint* __restrict__ arrg)
{
    __shared__ float4 par[128];
    __shared__ float  red[512];
    __shared__ ushort rev[512];

    int tid = threadIdx.x;
    int h   = blockIdx.x;
    int s   = blockIdx.y;

    if (tid < 128) {
        int n  = tid & 63;
        int ch = tid >> 6;
        const float* Ar = s ? A_re1 : A_re0;
        const float* Ai = s ? A_im1 : A_im0;
        const float* Cr = s ? C_re1 : C_re0;
        const float* Ci = s ? C_im1 : C_im0;
        const float* Ld = s ? log_dt1 : log_dt0;
        float dt = __expf(Ld[h]);
        float ar = Ar[h*NN + n], ai = Ai[h*NN + n];
        float cr = Cr[(ch*HH + h)*NN + n], ci = Ci[(ch*HH + h)*NN + n];
        float xr = dt * ar, xi = dt * ai;
        float phr = xi * 0.15915494f;
        float phf = phr - floorf(phr);
        float sn = __sinf(6.2831853f * phf);
        float cs = __cosf(6.2831853f * phf);
        float e  = __expf(xr);
        float er = e*cs - 1.f, ei = e*sn;
        float inv = 1.f / (ar*ar + ai*ai);
        float dr = (er*ar + ei*ai) * inv;
        float di = (ei*ar - er*ai) * inv;
        float Kr = 2.f*(cr*dr - ci*di);
        float Ki = 2.f*(cr*di + ci*dr);
        par[tid] = (float4){ xr, xi * 0.15915494f, Kr, Ki };
    }
    __syncthreads();

    {
        int l  = tid & 255;
        int ch = tid >> 8;
        float lf = (float)l;
#pragma unroll
        for (int nh = 0; nh < 2; ++nh) {
            const float4* pb = &par[ch*64 + nh*32];
            float acc = 0.f;
            for (int n = 0; n < 32; ++n) {
                float4 p = pb[n];
                float mag = __expf(p.x * lf);
                float ph  = p.y * lf;
                float phf = ph - floorf(ph);
                float ang = 6.2831853f * phf;
                acc += p.z * (mag * __cosf(ang)) - p.w * (mag * __sinf(ang));
            }
            if (nh == 0) red[tid] = acc;
            else {
                int ri = ch ? (256 + l) : (255 - l);
                rev[ri] = f2bf(red[tid] + acc);
            }
        }
    }
    __syncthreads();

    {
        int j  = tid & 255;
        uint lo, hi;
        if (tid < 256) { lo = rev[2*j];     hi = rev[2*j + 1]; }
        else           { lo = rev[2*j + 1]; hi = (j == 255) ? 0u : (uint)rev[2*j + 2]; }
        arrg[(s*HH + h)*512 + tid] = lo | (hi << 16);
    }
}

#define GL0(dst, addr)  asm volatile("global_load_dwordx4 %0, %1, off"           : "=v"(dst) : "v"(addr))
#define GL16(dst, addr) asm volatile("global_load_dwordx4 %0, %1, off offset:16" : "=v"(dst) : "v"(addr))
#define VMW(n) do { asm volatile("s_waitcnt vmcnt(" #n ")" ::: "memory"); \
                    __builtin_amdgcn_sched_barrier(0); } while (0)

// issue produce-B loads for (chunk kc, ys) into bank (N0,N1)
#define PISS(kc, ys, N0, N1) \
    { const float* a_ = rpP + (kc)*8192 + (ys)*32 + 8*q; GL0(N0, a_); GL16(N1, a_); }

// produce consume-side: A-frag(ys) from T2, cvt bank, 1 MFMA into APX
#define PCON(ys, C0, C1, CNT, APX)                                            \
    {                                                                         \
        int jj = jbP + 16*(ys);                                               \
        bf8 aF; uint* pa = (uint*)&aF;                                        \
        pa[0]=T2[jj]; pa[1]=T2[jj+1]; pa[2]=T2[jj+2]; pa[3]=T2[jj+3];         \
        VMW(CNT);                                                             \
        bf8 bB; uint* pb = (uint*)&bB;                                        \
        pb[0]=cvt_pk_bf16(C0.x,C0.y); pb[1]=cvt_pk_bf16(C0.z,C0.w);           \
        pb[2]=cvt_pk_bf16(C1.x,C1.y); pb[3]=cvt_pk_bf16(C1.z,C1.w);           \
        APX = MFMA(aF, bB, APX);                                              \
    }

// consume slice for (chunk k, ys): mi=ys&1, ni=ys>>1; ds_read at even ys
#define CSLICE(k, ys)                                                         \
    {                                                                         \
        if (((ys) & 1) == 0)                                                  \
            bC = *(const bf8*)&Wc[(k)&1][(16*((ys)>>1) + c)*WCP + 8*q];       \
        acc2[((ys)&1)*4 + ((ys)>>1)] =                                        \
            MFMA(win2[(2*(k) - ((ys)&1)) & 3], bC, acc2[((ys)&1)*4 + ((ys)>>1)]); \
    }

#define WROLL(t_)                                                             \
    { int jj = jb1 + 8*(t_); uint* pw = (uint*)&win2[(t_) & 3];               \
      pw[0]=T1[jj]; pw[1]=T1[jj+1]; pw[2]=T1[jj+2]; pw[3]=T1[jj+3]; }

// chunk body: consume chunk k while producing chunk k+1 (interleaved)
#define BODY(k)                                                               \
    {                                                                         \
        WROLL(2*(k)-1) WROLL(2*(k))                                           \
        bf8 bC;                                                               \
        PISS((k)+1, 0, P0, P1)                                                \
        PISS((k)+1, 1, Q0, Q1)  CSLICE(k,0)  PCON(0, P0, P1, 2, accpA)        \
        PISS((k)+1, 2, P0, P1)  CSLICE(k,1)  PCON(1, Q0, Q1, 2, accpB)        \
        PISS((k)+1, 3, Q0, Q1)  CSLICE(k,2)  PCON(2, P0, P1, 2, accpA)        \
        PISS((k)+1, 4, P0, P1)  CSLICE(k,3)  PCON(3, Q0, Q1, 2, accpB)        \
        PISS((k)+1, 5, Q0, Q1)  CSLICE(k,4)  PCON(4, P0, P1, 2, accpA)        \
        PISS((k)+1, 6, P0, P1)  CSLICE(k,5)  PCON(5, Q0, Q1, 2, accpB)        \
        PISS((k)+1, 7, Q0, Q1)  CSLICE(k,6)  PCON(6, P0, P1, 2, accpA)        \
                                CSLICE(k,7)  PCON(7, Q0, Q1, 0, accpB)        \
        _Pragma("unroll")                                                     \
        for (int r = 0; r < 4; ++r) {                                         \
            Wc[((k)+1)&1][(16*yb + 4*q + r)*WCP + 16*xh + c] =                \
                f2bf(accpA[r] + accpB[r]);                                    \
            accpA[r] = 0.f; accpB[r] = 0.f;                                   \
        }                                                                     \
        __syncthreads();                                                      \
    }

// Fused S4ND v7: block = (bh, y'-quarter 64). 512 thr / 8 waves, 24.6KB LDS.
// Per chunk k over x: consume(k) [Wc->MFMA->acc2] interleaved with
// produce(k+1) [u->cvt->MFMA->Wc] inside every wave.
__global__ __launch_bounds__(512, 4) void s4nd_v7(
    const float* __restrict__ u, const float* __restrict__ Dv,
    const uint* __restrict__ arrg, float* __restrict__ out)
{
    __shared__ ushort Wc[2][64 * WCP];    // 2 x 5120 B
    __shared__ uint   arr[2][512];        // 4096 B

    int tid = threadIdx.x;
    int j    = blockIdx.x;
    int xcd  = j & 7;
    int k0   = j >> 3;                    // 0..127
    int bh   = xcd * 32 + (k0 >> 2);
    int yq   = (k0 & 3) * 64;             // y' quarter offset
    int h    = bh & (HH - 1);

    arr[0][tid] = arrg[h*512 + tid];
    arr[1][tid] = arrg[(HH + h)*512 + tid];
    __syncthreads();

    int lane = tid & 63;
    int w = tid >> 6;                     // 0..7
    int c = lane & 15, q = lane >> 4;
    int yb = w & 3;                       // produce y'16-block
    int xh = w >> 2;                      // produce x-half of chunk

    const uint* T1 = &arr[0][(c & 1) ? 0 : 256];
    const uint* T2 = &arr[1][(c & 1) ? 0 : 256];
    int jbP = (255 - yq - 16*yb - c + 8*q) >> 1;   // produce A-frag base
    int jb1 = (255 - 32*w  - c + 8*q) >> 1;        // consume A-frag base

    const float* ub  = u + (size_t)bh * LL * LL;
    const float* rpP = ub + (size_t)(16*xh + c) * LL;   // produce B row
    float* yb_ = out + (size_t)bh * LL * LL;

    f32x4 acc2[8];                        // consume acc: [mi 2][ni 4]
#pragma unroll
    for (int i = 0; i < 8; ++i) acc2[i] = (f32x4){0.f,0.f,0.f,0.f};
    f32x4 accpA = (f32x4){0.f,0.f,0.f,0.f};
    f32x4 accpB = (f32x4){0.f,0.f,0.f,0.f};

    float4 P0, P1, Q0, Q1;
    bf8 win2[4];

    // ---- prologue: produce chunk 0 ----
    PISS(0, 0, P0, P1)
    PISS(0, 1, Q0, Q1)
    PCON(0, P0, P1, 2, accpA)  PISS(0, 2, P0, P1)
    PCON(1, Q0, Q1, 2, accpB)  PISS(0, 3, Q0, Q1)
    PCON(2, P0, P1, 2, accpA)  PISS(0, 4, P0, P1)
    PCON(3, Q0, Q1, 2, accpB)  PISS(0, 5, Q0, Q1)
    PCON(4, P0, P1, 2, accpA)  PISS(0, 6, P0, P1)
    PCON(5, Q0, Q1, 2, accpB)  PISS(0, 7, Q0, Q1)
    PCON(6, P0, P1, 2, accpA)
    PCON(7, Q0, Q1, 0, accpB)
#pragma unroll
    for (int r = 0; r < 4; ++r) {
        Wc[0][(16*yb + 4*q + r)*WCP + 16*xh + c] = f2bf(accpA[r] + accpB[r]);
        accpA[r] = 0.f; accpB[r] = 0.f;
    }
    __syncthreads();

    // ---- consume A-window preload (t = -1, 0) ----
    WROLL(-1) WROLL(0)

    // ---- chunks 0..6: consume k + produce k+1 ----
    BODY(0) BODY(1) BODY(2) BODY(3) BODY(4) BODY(5) BODY(6)

    // ---- chunk 7: consume only ----
    {
        WROLL(13) WROLL(14)
        bf8 bC;
        CSLICE(7,0) CSLICE(7,1) CSLICE(7,2) CSLICE(7,3)
        CSLICE(7,4) CSLICE(7,5) CSLICE(7,6) CSLICE(7,7)
    }

    // ---- epilogue: Y + D*u -> global ----
    float dh = Dv[h];
    float uh[32];
#pragma unroll
    for (int mi = 0; mi < 2; ++mi)
#pragma unroll
        for (int r = 0; r < 4; ++r) {
            int row = 32*w + 16*mi + 4*q + r;
#pragma unroll
            for (int ni = 0; ni < 4; ++ni)
                uh[mi*16 + r*4 + ni] = ub[(size_t)row*LL + yq + 16*ni + c];
        }
#pragma unroll
    for (int mi = 0; mi < 2; ++mi)
#pragma unroll
        for (int ni = 0; ni < 4; ++ni)
#pragma unroll
            for (int r = 0; r < 4; ++r) {
                int row = 32*w + 16*mi + 4*q + r;
                int col = yq + 16*ni + c;
                yb_[(size_t)row*LL + col] =
                    acc2[mi*4 + ni][r] + dh * uh[mi*16 + r*4 + ni];
            }
}

extern "C" void kernel_launch(void* const* d_in, const int* in_sizes, int n_in,
                              void* d_out, int out_size, void* d_ws, size_t ws_size,
                              hipStream_t stream)
{
    const float* u       = (const float*)d_in[0];
    const float* D       = (const float*)d_in[1];
    const float* A_re0   = (const float*)d_in[2];
    const float* A_im0   = (const float*)d_in[3];
    const float* C_re0   = (const float*)d_in[4];
    const float* C_im0   = (const float*)d_in[5];
    const float* log_dt0 = (const float*)d_in[6];
    const float* A_re1   = (const float*)d_in[7];
    const float* A_im1   = (const float*)d_in[8];
    const float* C_re1   = (const float*)d_in[9];
    const float* C_im1   = (const float*)d_in[10];
    const float* log_dt1 = (const float*)d_in[11];
    float* out = (float*)d_out;

    uint* arrg = (uint*)d_ws;   // 2*128*512 u32 = 512 KB

    ssm_gen_fast<<<dim3(HH, 2), 512, 0, stream>>>(
        A_re0, A_im0, C_re0, C_im0, log_dt0,
        A_re1, A_im1, C_re1, C_im1, log_dt1, arrg);
    s4nd_v7<<<1024, 512, 0, stream>>>(u, D, arrg, out);
}

// Round 21
// 44.310 us; speedup vs baseline: 3.5338x; 3.5338x over previous
//
#include <hip/hip_runtime.h>

#define HH 128
#define NN 64
#define LL 256
#define WP 280   // u16 pitch: 140 dwords = 12 mod 32 -> conflict-free b128 rows

typedef __attribute__((ext_vector_type(8))) short bf8;
typedef __attribute__((ext_vector_type(4))) float f32x4;

__device__ inline ushort f2bf(float f) {
    uint x = __float_as_uint(f);
    return (ushort)((x + 0x7fffu + ((x >> 16) & 1u)) >> 16);
}
__device__ inline uint cvt_pk_bf16(float lo, float hi) {
    uint r;
    asm volatile("v_cvt_pk_bf16_f32 %0, %1, %2" : "=v"(r) : "v"(lo), "v"(hi));
    return r;
}
#define MFMA(a,b,c) __builtin_amdgcn_mfma_f32_16x16x32_bf16((a),(b),(c),0,0,0)

// Tap generation, hw trig, one block per (h, s); n-loop split 2-way + LDS reduce.
// arrg[(s*HH+h)*512 + i] = rev[i] | rev[i+1]<<16, rev[i] = kcat_s[h][511-i].
__global__ __launch_bounds__(512) void ssm_gen_fast(
    const float* __restrict__ A_re0, const float* __restrict__ A_im0,
    const float* __restrict__ C_re0, const float* __restrict__ C_im0,
    const float* __restrict__ log_dt0,
    const float* __restrict__ A_re1, const float* __restrict__ A_im1,
    const float* __restrict__ C_re1, const float* __restrict__ C_im1,
    const float* __restrict__ log_dt1,
    uint* __restrict__ arrg)
{
    __shared__ float4 par[128];       // (ch,n) -> {xr, xi_rev, Kr2, Ki2}
    __shared__ float  red[512];       // partial sums
    __shared__ ushort rev[512];

    int tid = threadIdx.x;
    int h   = blockIdx.x;
    int s   = blockIdx.y;

    if (tid < 128) {
        int n  = tid & 63;
        int ch = tid >> 6;
        const float* Ar = s ? A_re1 : A_re0;
        const float* Ai = s ? A_im1 : A_im0;
        const float* Cr = s ? C_re1 : C_re0;
        const float* Ci = s ? C_im1 : C_im0;
        const float* Ld = s ? log_dt1 : log_dt0;
        float dt = __expf(Ld[h]);
        float ar = Ar[h*NN + n], ai = Ai[h*NN + n];
        float cr = Cr[(ch*HH + h)*NN + n], ci = Ci[(ch*HH + h)*NN + n];
        float xr = dt * ar, xi = dt * ai;
        float phr = xi * 0.15915494f;
        float phf = phr - floorf(phr);
        float sn = __sinf(6.2831853f * phf);
        float cs = __cosf(6.2831853f * phf);
        float e  = __expf(xr);
        float er = e*cs - 1.f, ei = e*sn;
        float inv = 1.f / (ar*ar + ai*ai);
        float dr = (er*ar + ei*ai) * inv;
        float di = (ei*ar - er*ai) * inv;
        float Kr = 2.f*(cr*dr - ci*di);
        float Ki = 2.f*(cr*di + ci*dr);
        par[tid] = (float4){ xr, xi * 0.15915494f, Kr, Ki };
    }
    __syncthreads();

    // thread = (nh, ch, l): 512 = 2 ch * 256 l, each does 32 n per nh pass
    {
        int l  = tid & 255;
        int ch = tid >> 8;        // 0..1
        float lf = (float)l;
#pragma unroll
        for (int nh = 0; nh < 2; ++nh) {
            // nh handled by looping: split 64 into two 32-chunks; partial in red
            const float4* pb = &par[ch*64 + nh*32];
            float acc = 0.f;
            for (int n = 0; n < 32; ++n) {
                float4 p = pb[n];
                float mag = __expf(p.x * lf);
                float ph  = p.y * lf;
                float phf = ph - floorf(ph);
                float ang = 6.2831853f * phf;
                acc += p.z * (mag * __cosf(ang)) - p.w * (mag * __sinf(ang));
            }
            if (nh == 0) red[tid] = acc;
            else {
                int ri = ch ? (256 + l) : (255 - l);
                rev[ri] = f2bf(red[tid] + acc);
            }
        }
    }
    __syncthreads();

    uint lo = rev[tid];
    uint hi = (tid < 511) ? (uint)rev[tid + 1] : 0u;
    arrg[(s*HH + h)*512 + tid] = lo | (hi << 16);
}

// Fused S4ND per (b, h, y-half), 512 threads / 8 waves, 2 blocks/CU.
__global__ __launch_bounds__(512, 4) void s4nd_v3(
    const float* __restrict__ u, const float* __restrict__ Dv,
    const uint* __restrict__ arrg, float* __restrict__ out)
{
    __shared__ ushort WT[128 * WP];       // 71680 B
    __shared__ uint   arr[2][512];        // 4096 B

    int tid = threadIdx.x;

    // XCD-pairing swizzle: both y-halves of a bh on the same XCD, adjacent.
    int j    = blockIdx.x;
    int xcd  = j & 7;
    int k    = j >> 3;
    int bh   = xcd * 32 + (k >> 1);
    int y0   = (k & 1) * 128;
    int h    = bh & (HH - 1);

    arr[0][tid] = arrg[h*512 + tid];
    arr[1][tid] = arrg[(HH + h)*512 + tid];
    __syncthreads();

    int lane = tid & 63;
    int w = tid >> 6;                 // 0..7
    int c = lane & 15, q = lane >> 4;

    f32x4 acc[16];
#pragma unroll
    for (int i = 0; i < 16; ++i) acc[i] = (f32x4){0.f,0.f,0.f,0.f};

    const float* ub = u + (size_t)bh * LL * LL;
    const float* rp0 = ub + (size_t)(w*32 +  0 + c) * LL;
    const float* rp1 = ub + (size_t)(w*32 + 16 + c) * LL;

    // ---- phase 1: forced 2-deep load pipeline, no barriers ----
    float4 A0, A1, A2, A3, B0, B1, B2, B3;
    {
        int yb = 8*q;
        A0 = *(const float4*)(rp0 + yb); A1 = *(const float4*)(rp0 + yb + 4);
        A2 = *(const float4*)(rp1 + yb); A3 = *(const float4*)(rp1 + yb + 4);
    }
#pragma unroll
    for (int kk = 0; kk < 8; ++kk) {
        if (kk < 7) {
            int ybn = (kk + 1)*32 + 8*q;
            B0 = *(const float4*)(rp0 + ybn); B1 = *(const float4*)(rp0 + ybn + 4);
            B2 = *(const float4*)(rp1 + ybn); B3 = *(const float4*)(rp1 + ybn + 4);
        }
        // pin the issue point: nothing below may move above, loads stay here
        __builtin_amdgcn_sched_barrier(0);
        bf8 b0, b1;
        uint* p0 = (uint*)&b0; uint* p1 = (uint*)&b1;
        p0[0] = cvt_pk_bf16(A0.x, A0.y); p0[1] = cvt_pk_bf16(A0.z, A0.w);
        p0[2] = cvt_pk_bf16(A1.x, A1.y); p0[3] = cvt_pk_bf16(A1.z, A1.w);
        p1[0] = cvt_pk_bf16(A2.x, A2.y); p1[1] = cvt_pk_bf16(A2.z, A2.w);
        p1[2] = cvt_pk_bf16(A3.x, A3.y); p1[3] = cvt_pk_bf16(A3.z, A3.w);
        int sbase = 255 - y0 - c + kk*32 + 8*q;
        __builtin_amdgcn_s_setprio(1);
#pragma unroll
        for (int mi = 0; mi < 8; ++mi) {
            int s0 = sbase - 16*mi;   // a[jj] = M2[y0+16mi+c][kk*32+8q+jj]
            bf8 a; uint* pa = (uint*)&a;
            pa[0] = arr[1][s0];     pa[1] = arr[1][s0 + 2];
            pa[2] = arr[1][s0 + 4]; pa[3] = arr[1][s0 + 6];
            acc[mi*2 + 0] = MFMA(a, b0, acc[mi*2 + 0]);
            acc[mi*2 + 1] = MFMA(a, b1, acc[mi*2 + 1]);
        }
        __builtin_amdgcn_s_setprio(0);
        A0 = B0; A1 = B1; A2 = B2; A3 = B3;
    }

    // ---- acc -> WT (bf16, linear cols, WP pitch handles banks) ----
#pragma unroll
    for (int mi = 0; mi < 8; ++mi)
#pragma unroll
        for (int ni = 0; ni < 2; ++ni)
#pragma unroll
            for (int r = 0; r < 4; ++r) {
                int row = 16*mi + 4*q + r;
                int col = w*32 + 16*ni + c;
                WT[row*WP + col] = f2bf(acc[mi*2 + ni][r]);
                acc[mi*2 + ni][r] = 0.f;
            }
    __syncthreads();

    // ---- phase 2: two ni-halves, u-prefetch early, stores spread ----
    int wm2 = (w >> 1) * 64, wn2 = (w & 1) * 64;
    float dh = Dv[h];
    float* yb_ = out + (size_t)bh * LL * LL;

#pragma unroll
    for (int half = 0; half < 2; ++half) {
        int nb = wn2 + half*32;       // y'-base of this half (2 ni blocks)

        // prefetch epilogue u for this half (lands under the kk loop)
        float uh[32];
#pragma unroll
        for (int mi = 0; mi < 4; ++mi)
#pragma unroll
            for (int r = 0; r < 4; ++r) {
                int row = wm2 + 16*mi + 4*q + r;
#pragma unroll
                for (int ni = 0; ni < 2; ++ni)
                    uh[(mi*4 + r)*2 + ni] = ub[(size_t)row*LL + y0 + nb + 16*ni + c];
            }

#pragma unroll
        for (int kk = 0; kk < 8; ++kk) {
            int xb = kk*32;
            bf8 b0, b1;
            b0 = *(const bf8*)&WT[(nb + c)*WP + xb + 8*q];
            b1 = *(const bf8*)&WT[(nb + 16 + c)*WP + xb + 8*q];
            int sbase = 255 - wm2 - c + xb + 8*q;
            __builtin_amdgcn_s_setprio(1);
#pragma unroll
            for (int mi = 0; mi < 4; ++mi) {
                int s0 = sbase - 16*mi;  // a[jj] = M1[wm2+16mi+c][xb+8q+jj]
                bf8 a; uint* pa = (uint*)&a;
                pa[0] = arr[0][s0];     pa[1] = arr[0][s0 + 2];
                pa[2] = arr[0][s0 + 4]; pa[3] = arr[0][s0 + 6];
                acc[mi*2 + 0] = MFMA(a, b0, acc[mi*2 + 0]);
                acc[mi*2 + 1] = MFMA(a, b1, acc[mi*2 + 1]);
            }
            __builtin_amdgcn_s_setprio(0);
        }

        // store this half (+D*u), reset acc
#pragma unroll
        for (int mi = 0; mi < 4; ++mi)
#pragma unroll
            for (int ni = 0; ni < 2; ++ni)
#pragma unroll
                for (int r = 0; r < 4; ++r) {
                    int row = wm2 + 16*mi + 4*q + r;
                    int col = y0 + nb + 16*ni + c;
                    yb_[(size_t)row*LL + col] =
                        acc[mi*2 + ni][r] + dh * uh[(mi*4 + r)*2 + ni];
                    acc[mi*2 + ni][r] = 0.f;
                }
    }
}

extern "C" void kernel_launch(void* const* d_in, const int* in_sizes, int n_in,
                              void* d_out, int out_size, void* d_ws, size_t ws_size,
                              hipStream_t stream)
{
    const float* u       = (const float*)d_in[0];
    const float* D       = (const float*)d_in[1];
    const float* A_re0   = (const float*)d_in[2];
    const float* A_im0   = (const float*)d_in[3];
    const float* C_re0   = (const float*)d_in[4];
    const float* C_im0   = (const float*)d_in[5];
    const float* log_dt0 = (const float*)d_in[6];
    const float* A_re1   = (const float*)d_in[7];
    const float* A_im1   = (const float*)d_in[8];
    const float* C_re1   = (const float*)d_in[9];
    const float* C_im1   = (const float*)d_in[10];
    const float* log_dt1 = (const float*)d_in[11];
    float* out = (float*)d_out;

    uint* arrg = (uint*)d_ws;   // 2*128*512 u32 = 512 KB

    ssm_gen_fast<<<dim3(HH, 2), 512, 0, stream>>>(
        A_re0, A_im0, C_re0, C_im0, log_dt0,
        A_re1, A_im1, C_re1, C_im1, log_dt1, arrg);
    s4nd_v3<<<512, 512, 0, stream>>>(u, D, arrg, out);
}